// Round 19
// baseline (94.849 us; speedup 1.0000x reference)
//
#include <hip/hip_runtime.h>
#include <hip/hip_bf16.h>
#include <math.h>

#define NTOK 10000
#define BATCH 2
#define CDIM 128
#define NHEAD 4
#define NPNT 20
#define DHEAD 32
#define HWDIM 100
#define MROWS (BATCH * NTOK)
#define OPAD 384   // 128 value rows + 4 heads x (40 off + 20 attn + 4 pad)
#define PHALO 4
#define TI 4        // token tile i-extent
#define TJ 8        // token tile j-extent
#define SPI 12      // TI + 2*PHALO (i-cells)
#define SPJ 16      // TJ + 2*PHALO (j-cells)
#define NPI 25      // 100 / TI
#define NPJ 13      // ceil(100 / TJ)
#define NCELL 192   // SPI*SPJ ; K = 192 = 6*32 exactly
#define WBS 200     // bf16 row stride (400B -> 2-way bank aliasing, free)

typedef __attribute__((ext_vector_type(8))) short short8v;
typedef __attribute__((ext_vector_type(4))) float f32x4;

__device__ __forceinline__ float asf(unsigned u) {
  union { unsigned u; float f; } c; c.u = u; return c.f;
}

// ---------------------------------------------------------------------------
// prep: blocks [0,384): Wcat row blk (bf16) + bcat[blk].
//   row < 128: W_val row. row in [128,384): h=(row-128)>>6, k=(row-128)&63:
//   k<40 -> W_off[h*40+k]; 40<=k<60 -> W_attn[h*20+k-40]; else zero pad.
// blocks [384,512): fold Wc = W2@W1 row -> Wc_bf, bc (for proj2).
// ---------------------------------------------------------------------------
__global__ __launch_bounds__(128) void prep_kernel(
    const float* __restrict__ W_val, const float* __restrict__ b_val,
    const float* __restrict__ W_off, const float* __restrict__ b_off,
    const float* __restrict__ W_attn, const float* __restrict__ b_attn,
    const float* __restrict__ W1, const float* __restrict__ b1,
    const float* __restrict__ W2, const float* __restrict__ b2,
    __hip_bfloat16* __restrict__ Wcat, float* __restrict__ bcat,
    __hip_bfloat16* __restrict__ Wc_bf, float* __restrict__ bc) {
  __shared__ float w2row[128];
  __shared__ float red[128];
  const int blk = blockIdx.x, c = threadIdx.x;
  if (blk < OPAD) {
    float v = 0.f, bv = 0.f;
    if (blk < 128) {
      v = W_val[blk * 128 + c]; bv = b_val[blk];
    } else {
      int h = (blk - 128) >> 6, k = (blk - 128) & 63;
      if (k < 40) { v = W_off[(h * 40 + k) * 128 + c]; bv = b_off[h * 40 + k]; }
      else if (k < 60) { v = W_attn[(h * 20 + k - 40) * 128 + c]; bv = b_attn[h * 20 + k - 40]; }
    }
    Wcat[(size_t)blk * 128 + c] = __float2bfloat16(v);
    if (c == 0) bcat[blk] = bv;
  } else {
    const int o = blk - OPAD;  // 0..127
    w2row[c] = W2[o * 128 + c];
    __syncthreads();
    float acc = 0.f;
    for (int k = 0; k < 128; ++k) acc += w2row[k] * W1[k * 128 + c];
    Wc_bf[(size_t)o * 128 + c] = __float2bfloat16(acc);
    red[c] = w2row[c] * b1[c];
    __syncthreads();
    for (int s = 64; s > 0; s >>= 1) {
      if (c < s) red[c] += red[c + s];
      __syncthreads();
    }
    if (c == 0) bc[o] = b2[o] + red[0];
  }
}

// ---------------------------------------------------------------------------
// proj1: 256 thr, grid (313,2). 64 rows x 192 outs (3 internal 64-out tiles).
// ---------------------------------------------------------------------------
__global__ __launch_bounds__(256) void proj1_kernel(
    const float* __restrict__ query, const float* __restrict__ qpos,
    const __hip_bfloat16* __restrict__ Wcat, const float* __restrict__ bcat,
    __hip_bfloat16* __restrict__ value, __hip_bfloat16* __restrict__ offb,
    float* __restrict__ attnb) {
  __shared__ __hip_bfloat16 qa[64][128];
  __shared__ __hip_bfloat16 wb[64][128];
  const int t = threadIdx.x;
  const int r0 = blockIdx.x * 64;

#pragma unroll
  for (int i = 0; i < 4; ++i) {
    int lin = t + 256 * i;
    int r = lin >> 4, g = lin & 15;
    int c = g << 3;
    float4 v0 = make_float4(0.f, 0.f, 0.f, 0.f);
    float4 v1 = make_float4(0.f, 0.f, 0.f, 0.f);
    if (r0 + r < MROWS) {
      const float* p = query + (size_t)(r0 + r) * CDIM + c;
      v0 = *(const float4*)p;
      v1 = *(const float4*)(p + 4);
      const float* p2 = qpos + (size_t)(r0 + r) * CDIM + c;
      float4 u0 = *(const float4*)p2;
      float4 u1 = *(const float4*)(p2 + 4);
      v0.x += u0.x; v0.y += u0.y; v0.z += u0.z; v0.w += u0.w;
      v1.x += u1.x; v1.y += u1.y; v1.z += u1.z; v1.w += u1.w;
    }
    __hip_bfloat16* dst = &qa[r][(g ^ (r & 7)) << 3];
    dst[0] = __float2bfloat16(v0.x); dst[1] = __float2bfloat16(v0.y);
    dst[2] = __float2bfloat16(v0.z); dst[3] = __float2bfloat16(v0.w);
    dst[4] = __float2bfloat16(v1.x); dst[5] = __float2bfloat16(v1.y);
    dst[6] = __float2bfloat16(v1.z); dst[7] = __float2bfloat16(v1.w);
  }
  __syncthreads();

  const int wid = t >> 6;
  const int lane = t & 63;
  const int wr = (wid >> 1) * 32;
  const int wc = (wid & 1) * 32;
  const int lrow = lane & 15;
  const int lk = lane >> 4;

  short8v afr[4][2];
  {
    int ra0 = wr + lrow, ra1 = wr + 16 + lrow;
#pragma unroll
    for (int kk = 0; kk < 4; ++kk) {
      int gb = kk * 4 + lk;
      afr[kk][0] = *(const short8v*)&qa[ra0][(gb ^ (ra0 & 7)) << 3];
      afr[kk][1] = *(const short8v*)&qa[ra1][(gb ^ (ra1 & 7)) << 3];
    }
  }

  for (int ti = 0; ti < 3; ++ti) {
    const int ot = blockIdx.y * 192 + ti * 64;
    __syncthreads();
#pragma unroll
    for (int i = 0; i < 4; ++i) {
      int lin = t + 256 * i;
      int r = lin >> 4, g = lin & 15;
      short8v w = *(const short8v*)(Wcat + (size_t)(ot + r) * 128 + (g << 3));
      *(short8v*)&wb[r][(g ^ (r & 7)) << 3] = w;
    }
    __syncthreads();

    f32x4 acc[2][2];
#pragma unroll
    for (int mi = 0; mi < 2; ++mi)
#pragma unroll
      for (int ni = 0; ni < 2; ++ni) acc[mi][ni] = (f32x4)(0.f);

#pragma unroll
    for (int kk = 0; kk < 4; ++kk) {
      const int gb = kk * 4 + lk;
      int rb0 = wc + lrow, rb1 = wc + 16 + lrow;
      short8v b0 = *(const short8v*)&wb[rb0][(gb ^ (rb0 & 7)) << 3];
      short8v b1 = *(const short8v*)&wb[rb1][(gb ^ (rb1 & 7)) << 3];
      acc[0][0] = __builtin_amdgcn_mfma_f32_16x16x32_bf16(afr[kk][0], b0, acc[0][0], 0, 0, 0);
      acc[0][1] = __builtin_amdgcn_mfma_f32_16x16x32_bf16(afr[kk][0], b1, acc[0][1], 0, 0, 0);
      acc[1][0] = __builtin_amdgcn_mfma_f32_16x16x32_bf16(afr[kk][1], b0, acc[1][0], 0, 0, 0);
      acc[1][1] = __builtin_amdgcn_mfma_f32_16x16x32_bf16(afr[kk][1], b1, acc[1][1], 0, 0, 0);
    }

#pragma unroll
    for (int mi = 0; mi < 2; ++mi) {
#pragma unroll
      for (int ni = 0; ni < 2; ++ni) {
#pragma unroll
        for (int reg = 0; reg < 4; ++reg) {
          int r = r0 + wr + mi * 16 + (lane >> 4) * 4 + reg;
          int o = ot + wc + ni * 16 + (lane & 15);
          if (r >= MROWS) continue;
          float v = acc[mi][ni][reg] + bcat[o];
          int b = r >= NTOK ? 1 : 0;
          int n = r - b * NTOK;
          if (o < 128) {
            int h = o >> 5, rem = o & 31;
            value[(((size_t)b * NHEAD + h) * NTOK + n) * 32 + rem] =
                __float2bfloat16(v);
          } else {
            int h = (o - 128) >> 6, k = (o - 128) & 63;
            size_t base = ((size_t)(b * NHEAD + h) * NTOK + n);
            if (k < 40) {
              offb[base * 40 + k] = __float2bfloat16(v);
            } else if (k < 60) {
              attnb[base * 20 + (k - 40)] = v;
            }
          }
        }
      }
    }
  }
}

// ---------------------------------------------------------------------------
// proj2: 256 thr, grid (313,2). out = A@Wc^T + bc + resid (Wc prefolded).
// ---------------------------------------------------------------------------
__global__ __launch_bounds__(256) void proj2_kernel(
    const __hip_bfloat16* __restrict__ outat,
    const __hip_bfloat16* __restrict__ Wc_bf, const float* __restrict__ bc,
    const float* __restrict__ resid, float* __restrict__ out) {
  __shared__ __hip_bfloat16 qa[64][128];
  __shared__ __hip_bfloat16 wb[64][128];
  const int t = threadIdx.x;
  const int r0 = blockIdx.x * 64;
  const int ot = blockIdx.y * 64;

#pragma unroll
  for (int i = 0; i < 4; ++i) {
    int lin = t + 256 * i;
    int r = lin >> 4, g = lin & 15;
    short8v v = (short8v)(short)0;
    if (r0 + r < MROWS)
      v = *(const short8v*)(outat + (size_t)(r0 + r) * CDIM + (g << 3));
    *(short8v*)&qa[r][(g ^ (r & 7)) << 3] = v;
  }
#pragma unroll
  for (int i = 0; i < 4; ++i) {
    int lin = t + 256 * i;
    int r = lin >> 4, g = lin & 15;
    short8v w = *(const short8v*)(Wc_bf + (size_t)(ot + r) * 128 + (g << 3));
    *(short8v*)&wb[r][(g ^ (r & 7)) << 3] = w;
  }
  __syncthreads();

  const int wid = t >> 6;
  const int lane = t & 63;
  const int wr = (wid >> 1) * 32;
  const int wc = (wid & 1) * 32;
  const int lrow = lane & 15;
  const int lk = lane >> 4;

  f32x4 acc[2][2];
#pragma unroll
  for (int mi = 0; mi < 2; ++mi)
#pragma unroll
    for (int ni = 0; ni < 2; ++ni) acc[mi][ni] = (f32x4)(0.f);

#pragma unroll
  for (int kk = 0; kk < 4; ++kk) {
    const int gb = kk * 4 + lk;
    int ra0 = wr + lrow, ra1 = wr + 16 + lrow;
    int rb0 = wc + lrow, rb1 = wc + 16 + lrow;
    short8v a0 = *(const short8v*)&qa[ra0][(gb ^ (ra0 & 7)) << 3];
    short8v a1 = *(const short8v*)&qa[ra1][(gb ^ (ra1 & 7)) << 3];
    short8v b0 = *(const short8v*)&wb[rb0][(gb ^ (rb0 & 7)) << 3];
    short8v b1 = *(const short8v*)&wb[rb1][(gb ^ (rb1 & 7)) << 3];
    acc[0][0] = __builtin_amdgcn_mfma_f32_16x16x32_bf16(a0, b0, acc[0][0], 0, 0, 0);
    acc[0][1] = __builtin_amdgcn_mfma_f32_16x16x32_bf16(a0, b1, acc[0][1], 0, 0, 0);
    acc[1][0] = __builtin_amdgcn_mfma_f32_16x16x32_bf16(a1, b0, acc[1][0], 0, 0, 0);
    acc[1][1] = __builtin_amdgcn_mfma_f32_16x16x32_bf16(a1, b1, acc[1][1], 0, 0, 0);
  }

#pragma unroll
  for (int mi = 0; mi < 2; ++mi) {
#pragma unroll
    for (int ni = 0; ni < 2; ++ni) {
#pragma unroll
      for (int reg = 0; reg < 4; ++reg) {
        int r = r0 + wr + mi * 16 + (lane >> 4) * 4 + reg;
        int o = ot + wc + ni * 16 + (lane & 15);
        if (r >= MROWS) continue;
        out[(size_t)r * CDIM + o] =
            acc[mi][ni][reg] + bc[o] + resid[(size_t)r * CDIM + o];
      }
    }
  }
}

// ---------------------------------------------------------------------------
// Sampling as MFMA, SELF-CONSISTENT tiling (fixes R17/R18's 4x16-vs-4x4
// mismatch that caused cross-block output stomping):
//   block = (slice, 4(i) x 8(j) token tile);  out[32 tok][32 d] =
//   W[32][192 cells] @ Vpatch[192][32],  K = 192 = 6x32 exactly.
// W = softmax-scaled bilinear weights scattered into Wf (f32 ds_add_f32),
// converted in place to bf16 Wb (register-staged, barrier-separated; Wb
// overlays Wf). Vpatch staged transposed [d][cell]. Tokens uniquely owned
// (i exact, j guarded by tv). Rare out-of-patch points handled exactly via
// fx. LDS = 24.6K(Wf) + 12.8K(Vt) + 4K(fx) = 41.5 KB.
// ---------------------------------------------------------------------------
__global__ __launch_bounds__(256) void sample_kernel(
    const __hip_bfloat16* __restrict__ value,
    const __hip_bfloat16* __restrict__ off, const float* __restrict__ attn,
    __hip_bfloat16* __restrict__ outat) {
  const int s = blockIdx.x & 7;
  const int pidx = blockIdx.x >> 3;  // 0..NPI*NPJ-1
  const int PI = pidx % NPI, PJ = pidx / NPI;
  const int I0 = PI * TI, J0 = PJ * TJ;
  const int b = s >> 2, h = s & 3;

  // 24576 (Wf f32[32][192], overlaid by Wb bf16[32][200]=12800B)
  // + 12800 (Vt bf16[32][200]) + 4096 (fx f32[32][32]) = 41472 B
  __shared__ __align__(16) char smem[24576 + 12800 + 4096];
  float* Wf = (float*)smem;
  __hip_bfloat16* Wb = (__hip_bfloat16*)smem;
  __hip_bfloat16* Vt = (__hip_bfloat16*)(smem + 24576);
  float* fx = (float*)(smem + 24576 + 12800);

  const __hip_bfloat16* vglob = value + (size_t)s * NTOK * DHEAD;
  const int t = threadIdx.x;

  // ---- issue patch global loads early (768 tasks = 3 x 256, exact) ----
  int4 vl[3];
#pragma unroll
  for (int it = 0; it < 3; ++it) {
    int task = t + 256 * it;
    int cell = task >> 2, part = task & 3;
    int py = cell / SPI, px = cell - py * SPI;  // py: j-dim, px: i-dim
    int gy = J0 - PHALO + py;
    int gx = I0 - PHALO + px;
    vl[it] = make_int4(0, 0, 0, 0);
    if (gy >= 0 && gy < HWDIM && gx >= 0 && gx < HWDIM)
      vl[it] = *(const int4*)(vglob + ((size_t)(gy * HWDIM + gx)) * DHEAD +
                              part * 8);
  }

  // token mapping: 32 tokens x 8 point-lanes
  const int tok = t >> 3, pg = t & 7;
  const int li = tok & 3, lj = tok >> 2;  // li 0..3, lj 0..7
  const int i = I0 + li, j = J0 + lj;
  const bool tv = (j < HWDIM);
  const int n = tv ? (i * HWDIM + j) : 0;
  unsigned ofu[3];
  float atf[3];
  int np = 0;
  {
    const unsigned* ob = (const unsigned*)(off + ((size_t)s * NTOK + n) * 40);
    const float* ab = attn + ((size_t)s * NTOK + n) * 20;
#pragma unroll
    for (int k = 0; k < 3; ++k) {
      int p = pg + 8 * k;
      if (p < NPNT) {
        ofu[np] = ob[p];
        atf[np] = ab[p];
        ++np;
      }
    }
  }

  // ---- zero Wf (1536 float4 = 6 x 256) and fx (256 float4) ----
  {
    float4 z4 = make_float4(0.f, 0.f, 0.f, 0.f);
    float4* wf4 = (float4*)Wf;
#pragma unroll
    for (int it = 0; it < 6; ++it) wf4[t + 256 * it] = z4;
    ((float4*)fx)[t] = z4;
  }

  // softmax exp (logits small; exact-safe); sum over 8 point-lanes
  float ssum = 0.f;
  for (int k = 0; k < np; ++k) { atf[k] = __expf(atf[k]); ssum += atf[k]; }
  ssum += __shfl_xor(ssum, 1);
  ssum += __shfl_xor(ssum, 2);
  ssum += __shfl_xor(ssum, 4);
  const float inv = tv ? (1.f / ssum) : 0.f;

  __syncthreads();

  // ---- write Vt transposed: Vt[d][cell] ----
#pragma unroll
  for (int it = 0; it < 3; ++it) {
    int task = t + 256 * it;
    int cell = task >> 2, part = task & 3;
    union { int4 v4; __hip_bfloat16 hh[8]; } u;
    u.v4 = vl[it];
    int d0 = part * 8;
#pragma unroll
    for (int k = 0; k < 8; ++k) Vt[(d0 + k) * WBS + cell] = u.hh[k];
  }

  // ---- scatter softmax-scaled bilinear weights into Wf ----
  const float fi = (float)i, fj = (float)j;
  unsigned oob = 0;
  if (tv) {
    for (int k = 0; k < np; ++k) {
      const unsigned up = ofu[k];
      float x = fi + asf(up << 16);           // i-dim
      float y = fj + asf(up & 0xFFFF0000u);   // j-dim
      float aw = atf[k] * inv;
      float x0f = floorf(x), y0f = floorf(y);
      int ix0 = (int)x0f, iy0 = (int)y0f;
      float wx1 = x - x0f, wy1 = y - y0f;
      float wx0 = 1.f - wx1, wy0 = 1.f - wy1;
      int ly = iy0 - (J0 - PHALO);   // j-cell
      int lx = ix0 - (I0 - PHALO);   // i-cell
      if ((unsigned)ly <= SPJ - 2 && (unsigned)lx <= SPI - 2) {
        int cell = ly * SPI + lx;
        float wya = aw * wy0, wyb = aw * wy1;
        atomicAdd(&Wf[tok * NCELL + cell], wya * wx0);
        atomicAdd(&Wf[tok * NCELL + cell + 1], wya * wx1);
        atomicAdd(&Wf[tok * NCELL + cell + SPI], wyb * wx0);
        atomicAdd(&Wf[tok * NCELL + cell + SPI + 1], wyb * wx1);
      } else {
        oob |= 1u << k;
      }
    }
    if (oob) {  // rare exact fallback -> fx
      for (int k = 0; k < np; ++k) {
        if (!(oob & (1u << k))) continue;
        const unsigned up = ofu[k];
        float x = fi + asf(up << 16);
        float y = fj + asf(up & 0xFFFF0000u);
        float aw = atf[k] * inv;
        float x0f = floorf(x), y0f = floorf(y);
        int ix0 = (int)x0f, iy0 = (int)y0f;
        float wx1 = x - x0f, wy1 = y - y0f;
        float wx0 = 1.f - wx1, wy0 = 1.f - wy1;
        float wgt[4] = {aw * wy0 * wx0, aw * wy0 * wx1, aw * wy1 * wx0,
                        aw * wy1 * wx1};
        for (int cy = 0; cy < 2; ++cy) {
          int iy = iy0 + cy;
          if (iy < 0 || iy >= HWDIM) continue;
          for (int cx = 0; cx < 2; ++cx) {
            int ix = ix0 + cx;
            if (ix < 0 || ix >= HWDIM) continue;
            float w = wgt[cy * 2 + cx];
            const __hip_bfloat16* vp =
                vglob + ((size_t)(iy * HWDIM + ix)) * DHEAD;
            for (int d = 0; d < 32; ++d)
              atomicAdd(&fx[tok * 32 + d], w * __bfloat162float(vp[d]));
          }
        }
      }
    }
  }
  __syncthreads();

  // ---- in-place Wf(f32) -> Wb(bf16): register-stage, barrier, write ----
  {
    int r = t & 31, chunk = t >> 5;  // 8 chunks x 24 cols = 192
    int c0 = chunk * 24;
    float wreg[24];
#pragma unroll
    for (int cc = 0; cc < 24; ++cc) wreg[cc] = Wf[r * NCELL + c0 + cc];
    __syncthreads();  // all Wf reads complete before overlay writes
#pragma unroll
    for (int cc = 0; cc < 24; ++cc)
      Wb[r * WBS + c0 + cc] = __float2bfloat16(wreg[cc]);
  }
  __syncthreads();

  // ---- MFMA: 4 waves; wave (wr,wc) = 16 tok x 16 d; 6 K-steps ----
  const int wid = t >> 6;
  const int lane = t & 63;
  const int wr = (wid >> 1) * 16;
  const int wc = (wid & 1) * 16;
  const int arow = wr + (lane & 15);
  const int bcol = wc + (lane & 15);
  const int kbase = (lane >> 4) * 8;
  f32x4 acc = (f32x4)(0.f);
#pragma unroll
  for (int ks = 0; ks < 6; ++ks) {
    short8v a = *(const short8v*)&Wb[arow * WBS + ks * 32 + kbase];
    short8v bfr = *(const short8v*)&Vt[bcol * WBS + ks * 32 + kbase];
    acc = __builtin_amdgcn_mfma_f32_16x16x32_bf16(a, bfr, acc, 0, 0, 0);
  }

  // epilogue: C/D col = lane&15 (d), row = (lane>>4)*4+reg (token) + fixup
#pragma unroll
  for (int reg = 0; reg < 4; ++reg) {
    int tk = wr + (lane >> 4) * 4 + reg;
    int d = bcol;
    int jj = J0 + (tk >> 2);
    if (jj >= HWDIM) continue;
    int tn = (I0 + (tk & 3)) * HWDIM + jj;
    float v = acc[reg] + fx[tk * 32 + d];
    outat[((size_t)b * NTOK + tn) * CDIM + h * DHEAD + d] = __float2bfloat16(v);
  }
}

extern "C" void kernel_launch(void* const* d_in, const int* in_sizes, int n_in,
                              void* d_out, int out_size, void* d_ws,
                              size_t ws_size, hipStream_t stream) {
  const float* query = (const float*)d_in[0];
  const float* query_pos = (const float*)d_in[1];
  const float* W_val = (const float*)d_in[2];
  const float* b_val = (const float*)d_in[3];
  const float* W_off = (const float*)d_in[4];
  const float* b_off = (const float*)d_in[5];
  const float* W_attn = (const float*)d_in[6];
  const float* b_attn = (const float*)d_in[7];
  const float* W_out1 = (const float*)d_in[8];
  const float* b_out1 = (const float*)d_in[9];
  const float* W_out2 = (const float*)d_in[10];
  const float* b_out2 = (const float*)d_in[11];
  float* out = (float*)d_out;

  char* ws = (char*)d_ws;
  __hip_bfloat16* value = (__hip_bfloat16*)ws;  // (B*NH,N,32) bf16
  ws += (size_t)MROWS * CDIM * 2;
  __hip_bfloat16* offb = (__hip_bfloat16*)ws;   // (B*NH,N,40) bf16
  ws += (size_t)MROWS * 160 * 2;
  float* attnb = (float*)ws;                    // (B*NH,N,20) f32
  ws += (size_t)MROWS * 80 * 4;
  __hip_bfloat16* outat = (__hip_bfloat16*)ws;  // (B,N,C) bf16
  ws += (size_t)MROWS * CDIM * 2;
  float* bcat = (float*)ws; ws += OPAD * 4;
  float* bc = (float*)ws; ws += 128 * 4;
  __hip_bfloat16* Wcat = (__hip_bfloat16*)ws; ws += (size_t)OPAD * 128 * 2;
  __hip_bfloat16* Wc_bf = (__hip_bfloat16*)ws;

  prep_kernel<<<OPAD + 128, 128, 0, stream>>>(
      W_val, b_val, W_off, b_off, W_attn, b_attn, W_out1, b_out1, W_out2,
      b_out2, Wcat, bcat, Wc_bf, bc);

  proj1_kernel<<<dim3(313, 2), 256, 0, stream>>>(query, query_pos, Wcat, bcat,
                                                 value, offb, attnb);

  sample_kernel<<<8 * NPI * NPJ, 256, 0, stream>>>(value, offb, attnb, outat);

  proj2_kernel<<<dim3(313, 2), 256, 0, stream>>>(outat, Wc_bf, bc, query, out);
}

// Round 20
// 59.067 us; speedup vs baseline: 1.6058x; 1.6058x over previous
//
#include <hip/hip_runtime.h>
#include <hip/hip_bf16.h>
#include <math.h>

#define NTOK 10000
#define BATCH 2
#define CDIM 128
#define NHEAD 4
#define NPNT 20
#define DHEAD 32
#define HWDIM 100
#define MROWS (BATCH * NTOK)
#define OPAD 384   // 128 value rows + 4 heads x (40 off + 20 attn + 4 pad)
#define PHALO 4
#define TTILE 4    // 4x4 tokens per patch
#define SPD 12     // TTILE + 2*PHALO
#define NPT 25     // 100 / TTILE
#define CELLPAD 40 // bf16 per cell in LDS (stride 80B: 16B-aligned)

typedef __attribute__((ext_vector_type(8))) short short8v;
typedef __attribute__((ext_vector_type(4))) short short4v;
typedef __attribute__((ext_vector_type(4))) float f32x4;

__device__ __forceinline__ float asf(unsigned u) {
  union { unsigned u; float f; } c; c.u = u; return c.f;
}

// unpack 8 bf16 (16B) and accumulate w * g into two f32x4 accumulators
__device__ __forceinline__ void acc_cell(const __hip_bfloat16* p, float w,
                                         f32x4& a0, f32x4& a1) {
  int4 u = *(const int4*)p;
  f32x4 g0, g1;
  g0.x = asf(((unsigned)u.x) << 16); g0.y = asf(((unsigned)u.x) & 0xFFFF0000u);
  g0.z = asf(((unsigned)u.y) << 16); g0.w = asf(((unsigned)u.y) & 0xFFFF0000u);
  g1.x = asf(((unsigned)u.z) << 16); g1.y = asf(((unsigned)u.z) & 0xFFFF0000u);
  g1.z = asf(((unsigned)u.w) << 16); g1.w = asf(((unsigned)u.w) & 0xFFFF0000u);
  a0 += g0 * w;
  a1 += g1 * w;
}

// ---------------------------------------------------------------------------
// prep: blocks [0,384): Wcat row blk (bf16) + bcat[blk].
//   row < 128: W_val row. row in [128,384): h=(row-128)>>6, k=(row-128)&63:
//   k<40 -> W_off[h*40+k]; 40<=k<60 -> W_attn[h*20+k-40]; else zero pad.
// blocks [384,512): fold Wc = W2@W1 row -> Wc_bf, bc (for proj2).
// ---------------------------------------------------------------------------
__global__ __launch_bounds__(128) void prep_kernel(
    const float* __restrict__ W_val, const float* __restrict__ b_val,
    const float* __restrict__ W_off, const float* __restrict__ b_off,
    const float* __restrict__ W_attn, const float* __restrict__ b_attn,
    const float* __restrict__ W1, const float* __restrict__ b1,
    const float* __restrict__ W2, const float* __restrict__ b2,
    __hip_bfloat16* __restrict__ Wcat, float* __restrict__ bcat,
    __hip_bfloat16* __restrict__ Wc_bf, float* __restrict__ bc) {
  __shared__ float w2row[128];
  __shared__ float red[128];
  const int blk = blockIdx.x, c = threadIdx.x;
  if (blk < OPAD) {
    float v = 0.f, bv = 0.f;
    if (blk < 128) {
      v = W_val[blk * 128 + c]; bv = b_val[blk];
    } else {
      int h = (blk - 128) >> 6, k = (blk - 128) & 63;
      if (k < 40) { v = W_off[(h * 40 + k) * 128 + c]; bv = b_off[h * 40 + k]; }
      else if (k < 60) { v = W_attn[(h * 20 + k - 40) * 128 + c]; bv = b_attn[h * 20 + k - 40]; }
    }
    Wcat[(size_t)blk * 128 + c] = __float2bfloat16(v);
    if (c == 0) bcat[blk] = bv;
  } else {
    const int o = blk - OPAD;  // 0..127
    w2row[c] = W2[o * 128 + c];
    __syncthreads();
    float acc = 0.f;
    for (int k = 0; k < 128; ++k) acc += w2row[k] * W1[k * 128 + c];
    Wc_bf[(size_t)o * 128 + c] = __float2bfloat16(acc);
    red[c] = w2row[c] * b1[c];
    __syncthreads();
    for (int s = 64; s > 0; s >>= 1) {
      if (c < s) red[c] += red[c + s];
      __syncthreads();
    }
    if (c == 0) bc[o] = b2[o] + red[0];
  }
}

// ---------------------------------------------------------------------------
// proj1: 256 thr, grid (313,2). 64 rows x 192 outs (3 internal 64-out tiles).
// ---------------------------------------------------------------------------
__global__ __launch_bounds__(256) void proj1_kernel(
    const float* __restrict__ query, const float* __restrict__ qpos,
    const __hip_bfloat16* __restrict__ Wcat, const float* __restrict__ bcat,
    __hip_bfloat16* __restrict__ value, __hip_bfloat16* __restrict__ offb,
    float* __restrict__ attnb) {
  __shared__ __hip_bfloat16 qa[64][128];
  __shared__ __hip_bfloat16 wb[64][128];
  const int t = threadIdx.x;
  const int r0 = blockIdx.x * 64;

#pragma unroll
  for (int i = 0; i < 4; ++i) {
    int lin = t + 256 * i;
    int r = lin >> 4, g = lin & 15;
    int c = g << 3;
    float4 v0 = make_float4(0.f, 0.f, 0.f, 0.f);
    float4 v1 = make_float4(0.f, 0.f, 0.f, 0.f);
    if (r0 + r < MROWS) {
      const float* p = query + (size_t)(r0 + r) * CDIM + c;
      v0 = *(const float4*)p;
      v1 = *(const float4*)(p + 4);
      const float* p2 = qpos + (size_t)(r0 + r) * CDIM + c;
      float4 u0 = *(const float4*)p2;
      float4 u1 = *(const float4*)(p2 + 4);
      v0.x += u0.x; v0.y += u0.y; v0.z += u0.z; v0.w += u0.w;
      v1.x += u1.x; v1.y += u1.y; v1.z += u1.z; v1.w += u1.w;
    }
    __hip_bfloat16* dst = &qa[r][(g ^ (r & 7)) << 3];
    dst[0] = __float2bfloat16(v0.x); dst[1] = __float2bfloat16(v0.y);
    dst[2] = __float2bfloat16(v0.z); dst[3] = __float2bfloat16(v0.w);
    dst[4] = __float2bfloat16(v1.x); dst[5] = __float2bfloat16(v1.y);
    dst[6] = __float2bfloat16(v1.z); dst[7] = __float2bfloat16(v1.w);
  }
  __syncthreads();

  const int wid = t >> 6;
  const int lane = t & 63;
  const int wr = (wid >> 1) * 32;
  const int wc = (wid & 1) * 32;
  const int lrow = lane & 15;
  const int lk = lane >> 4;

  short8v afr[4][2];
  {
    int ra0 = wr + lrow, ra1 = wr + 16 + lrow;
#pragma unroll
    for (int kk = 0; kk < 4; ++kk) {
      int gb = kk * 4 + lk;
      afr[kk][0] = *(const short8v*)&qa[ra0][(gb ^ (ra0 & 7)) << 3];
      afr[kk][1] = *(const short8v*)&qa[ra1][(gb ^ (ra1 & 7)) << 3];
    }
  }

  for (int ti = 0; ti < 3; ++ti) {
    const int ot = blockIdx.y * 192 + ti * 64;
    __syncthreads();
#pragma unroll
    for (int i = 0; i < 4; ++i) {
      int lin = t + 256 * i;
      int r = lin >> 4, g = lin & 15;
      short8v w = *(const short8v*)(Wcat + (size_t)(ot + r) * 128 + (g << 3));
      *(short8v*)&wb[r][(g ^ (r & 7)) << 3] = w;
    }
    __syncthreads();

    f32x4 acc[2][2];
#pragma unroll
    for (int mi = 0; mi < 2; ++mi)
#pragma unroll
      for (int ni = 0; ni < 2; ++ni) acc[mi][ni] = (f32x4)(0.f);

#pragma unroll
    for (int kk = 0; kk < 4; ++kk) {
      const int gb = kk * 4 + lk;
      int rb0 = wc + lrow, rb1 = wc + 16 + lrow;
      short8v b0 = *(const short8v*)&wb[rb0][(gb ^ (rb0 & 7)) << 3];
      short8v b1 = *(const short8v*)&wb[rb1][(gb ^ (rb1 & 7)) << 3];
      acc[0][0] = __builtin_amdgcn_mfma_f32_16x16x32_bf16(afr[kk][0], b0, acc[0][0], 0, 0, 0);
      acc[0][1] = __builtin_amdgcn_mfma_f32_16x16x32_bf16(afr[kk][0], b1, acc[0][1], 0, 0, 0);
      acc[1][0] = __builtin_amdgcn_mfma_f32_16x16x32_bf16(afr[kk][1], b0, acc[1][0], 0, 0, 0);
      acc[1][1] = __builtin_amdgcn_mfma_f32_16x16x32_bf16(afr[kk][1], b1, acc[1][1], 0, 0, 0);
    }

#pragma unroll
    for (int mi = 0; mi < 2; ++mi) {
#pragma unroll
      for (int ni = 0; ni < 2; ++ni) {
#pragma unroll
        for (int reg = 0; reg < 4; ++reg) {
          int r = r0 + wr + mi * 16 + (lane >> 4) * 4 + reg;
          int o = ot + wc + ni * 16 + (lane & 15);
          if (r >= MROWS) continue;
          float v = acc[mi][ni][reg] + bcat[o];
          int b = r >= NTOK ? 1 : 0;
          int n = r - b * NTOK;
          if (o < 128) {
            int h = o >> 5, rem = o & 31;
            value[(((size_t)b * NHEAD + h) * NTOK + n) * 32 + rem] =
                __float2bfloat16(v);
          } else {
            int h = (o - 128) >> 6, k = (o - 128) & 63;
            size_t base = ((size_t)(b * NHEAD + h) * NTOK + n);
            if (k < 40) {
              offb[base * 40 + k] = __float2bfloat16(v);
            } else if (k < 60) {
              attnb[base * 20 + (k - 40)] = v;
            }
          }
        }
      }
    }
  }
}

// ---------------------------------------------------------------------------
// proj2: 256 thr, grid (313,2). out = A@Wc^T + bc + resid (Wc prefolded).
// ---------------------------------------------------------------------------
__global__ __launch_bounds__(256) void proj2_kernel(
    const __hip_bfloat16* __restrict__ outat,
    const __hip_bfloat16* __restrict__ Wc_bf, const float* __restrict__ bc,
    const float* __restrict__ resid, float* __restrict__ out) {
  __shared__ __hip_bfloat16 qa[64][128];
  __shared__ __hip_bfloat16 wb[64][128];
  const int t = threadIdx.x;
  const int r0 = blockIdx.x * 64;
  const int ot = blockIdx.y * 64;

#pragma unroll
  for (int i = 0; i < 4; ++i) {
    int lin = t + 256 * i;
    int r = lin >> 4, g = lin & 15;
    short8v v = (short8v)(short)0;
    if (r0 + r < MROWS)
      v = *(const short8v*)(outat + (size_t)(r0 + r) * CDIM + (g << 3));
    *(short8v*)&qa[r][(g ^ (r & 7)) << 3] = v;
  }
#pragma unroll
  for (int i = 0; i < 4; ++i) {
    int lin = t + 256 * i;
    int r = lin >> 4, g = lin & 15;
    short8v w = *(const short8v*)(Wc_bf + (size_t)(ot + r) * 128 + (g << 3));
    *(short8v*)&wb[r][(g ^ (r & 7)) << 3] = w;
  }
  __syncthreads();

  const int wid = t >> 6;
  const int lane = t & 63;
  const int wr = (wid >> 1) * 32;
  const int wc = (wid & 1) * 32;
  const int lrow = lane & 15;
  const int lk = lane >> 4;

  f32x4 acc[2][2];
#pragma unroll
  for (int mi = 0; mi < 2; ++mi)
#pragma unroll
    for (int ni = 0; ni < 2; ++ni) acc[mi][ni] = (f32x4)(0.f);

#pragma unroll
  for (int kk = 0; kk < 4; ++kk) {
    const int gb = kk * 4 + lk;
    int ra0 = wr + lrow, ra1 = wr + 16 + lrow;
    int rb0 = wc + lrow, rb1 = wc + 16 + lrow;
    short8v a0 = *(const short8v*)&qa[ra0][(gb ^ (ra0 & 7)) << 3];
    short8v a1 = *(const short8v*)&qa[ra1][(gb ^ (ra1 & 7)) << 3];
    short8v b0 = *(const short8v*)&wb[rb0][(gb ^ (rb0 & 7)) << 3];
    short8v b1 = *(const short8v*)&wb[rb1][(gb ^ (rb1 & 7)) << 3];
    acc[0][0] = __builtin_amdgcn_mfma_f32_16x16x32_bf16(a0, b0, acc[0][0], 0, 0, 0);
    acc[0][1] = __builtin_amdgcn_mfma_f32_16x16x32_bf16(a0, b1, acc[0][1], 0, 0, 0);
    acc[1][0] = __builtin_amdgcn_mfma_f32_16x16x32_bf16(a1, b0, acc[1][0], 0, 0, 0);
    acc[1][1] = __builtin_amdgcn_mfma_f32_16x16x32_bf16(a1, b1, acc[1][1], 0, 0, 0);
  }

#pragma unroll
  for (int mi = 0; mi < 2; ++mi) {
#pragma unroll
    for (int ni = 0; ni < 2; ++ni) {
#pragma unroll
      for (int reg = 0; reg < 4; ++reg) {
        int r = r0 + wr + mi * 16 + (lane >> 4) * 4 + reg;
        int o = ot + wc + ni * 16 + (lane & 15);
        if (r >= MROWS) continue;
        out[(size_t)r * CDIM + o] =
            acc[mi][ni][reg] + bc[o] + resid[(size_t)r * CDIM + o];
      }
    }
  }
}

// ---------------------------------------------------------------------------
// Sampling, point-split: 16 lanes/token = 4 point-groups (5 points each) x
// 4 dim-groups (8 dims each). Grid 5000 blocks (4x4-token tiles, 12x12 halo
// patch, 11.5 KB LDS). Deferred softmax: each lane exps its 5 logits;
// accumulators AND exp-sum reduced across point-groups with __shfl_xor(4,8).
// pg==0 lanes store. Hoisted off/attn loads; branchy rare global fallback.
// ---------------------------------------------------------------------------
__global__ __launch_bounds__(256) void sample_kernel(
    const __hip_bfloat16* __restrict__ value,
    const __hip_bfloat16* __restrict__ off, const float* __restrict__ attn,
    __hip_bfloat16* __restrict__ outat) {
  const int s = blockIdx.x & 7;
  const int pidx = blockIdx.x >> 3;  // 0..624
  const int PI = pidx % NPT, PJ = pidx / NPT;
  const int I0 = PI * TTILE, J0 = PJ * TTILE;
  const int b = s >> 2, h = s & 3;

  __shared__ __hip_bfloat16 patch[SPD * SPD][CELLPAD];
  const __hip_bfloat16* vglob = value + (size_t)s * NTOK * DHEAD;

  const int t = threadIdx.x;
  const int lane16 = t & 15;
  const int dg = lane16 & 3;   // dim group: 8 dims at dg*8
  const int pg = lane16 >> 2;  // point group: points pg*5 .. pg*5+4
  const int tok = t >> 4;      // 0..15
  const int li = tok & 3, lj = tok >> 2;
  const int i = I0 + li, j = J0 + lj;
  const int n = i * HWDIM + j;

  // hoisted per-lane loads: 5 offset-pairs (u32) + 5 attn logits for this pg
  unsigned ofu[5];
  float atf[5];
  {
    const unsigned* ob =
        (const unsigned*)(off + ((size_t)s * NTOK + n) * 40) + pg * 5;
    const float* ab = attn + ((size_t)s * NTOK + n) * 20 + pg * 5;
#pragma unroll
    for (int k = 0; k < 5; ++k) { ofu[k] = ob[k]; atf[k] = ab[k]; }
  }

  // stage patch: 144 cells x 4 granule-parts = 576 over 256 thr
#pragma unroll
  for (int it = 0; it < 3; ++it) {
    int lin = t + 256 * it;
    if (lin < SPD * SPD * 4) {
      int cell = lin >> 2, part = lin & 3;
      int py = cell / SPD, px = cell - py * SPD;
      int gy = J0 - PHALO + py;
      int gx = I0 - PHALO + px;
      short8v v = (short8v)(short)0;
      if (gy >= 0 && gy < HWDIM && gx >= 0 && gx < HWDIM)
        v = *(const short8v*)(vglob + ((size_t)(gy * HWDIM + gx)) * DHEAD +
                              part * 8);
      *(short8v*)&patch[cell][part * 8] = v;
    }
  }
  __syncthreads();

  float ssum = 0.f;
#pragma unroll
  for (int k = 0; k < 5; ++k) {
    atf[k] = __expf(atf[k]);
    ssum += atf[k];
  }

  const float fi = (float)i, fj = (float)j;
  f32x4 a0 = (f32x4)(0.f), a1 = (f32x4)(0.f);
  f32x4 e0 = (f32x4)(0.f), e1 = (f32x4)(0.f);
#pragma unroll
  for (int k = 0; k < 5; ++k) {
    const unsigned up = ofu[k];
    float x = fi + asf(up << 16);
    float y = fj + asf(up & 0xFFFF0000u);
    float aw = atf[k];
    float x0f = floorf(x), y0f = floorf(y);
    int ix0 = (int)x0f, iy0 = (int)y0f;
    float wx1 = x - x0f, wy1 = y - y0f;
    float wx0 = 1.f - wx1, wy0 = 1.f - wy1;
    float wya = aw * wy0, wyb = aw * wy1;
    float w00 = wya * wx0, w01 = wya * wx1;
    float w10 = wyb * wx0, w11 = wyb * wx1;
    int ly = iy0 - (J0 - PHALO);
    int lx = ix0 - (I0 - PHALO);
    if ((unsigned)ly <= SPD - 2 && (unsigned)lx <= SPD - 2) {
      const __hip_bfloat16* pb = &patch[ly * SPD + lx][dg * 8];
      acc_cell(pb, w00, a0, a1);
      acc_cell(pb + CELLPAD, w01, e0, e1);
      acc_cell(pb + SPD * CELLPAD, w10, a0, a1);
      acc_cell(pb + SPD * CELLPAD + CELLPAD, w11, e0, e1);
    } else {
      // rare out-of-patch fallback: direct gather with bounds checks
      float wgt[4] = {w00, w01, w10, w11};
#pragma unroll
      for (int cy = 0; cy < 2; ++cy) {
        int iy = iy0 + cy;
        if (iy < 0 || iy >= HWDIM) continue;
#pragma unroll
        for (int cx = 0; cx < 2; ++cx) {
          int ix = ix0 + cx;
          if (ix < 0 || ix >= HWDIM) continue;
          acc_cell(vglob + ((size_t)(iy * HWDIM + ix)) * DHEAD + dg * 8,
                   wgt[cy * 2 + cx], a0, a1);
        }
      }
    }
  }
  f32x4 r0 = a0 + e0;
  f32x4 r1 = a1 + e1;

  // reduce accumulators + exp-sum across the 4 point-groups (lanes ^4, ^8)
#pragma unroll
  for (int m = 4; m <= 8; m <<= 1) {
#pragma unroll
    for (int el = 0; el < 4; ++el) {
      r0[el] += __shfl_xor(r0[el], m);
      r1[el] += __shfl_xor(r1[el], m);
    }
    ssum += __shfl_xor(ssum, m);
  }

  if (pg == 0) {
    const float inv = 1.f / ssum;
    union { short8v v8; __hip_bfloat16 hh[8]; } o;
#pragma unroll
    for (int k = 0; k < 4; ++k) {
      o.hh[k] = __float2bfloat16(r0[k] * inv);
      o.hh[4 + k] = __float2bfloat16(r1[k] * inv);
    }
    *(short8v*)(outat + ((size_t)b * NTOK + n) * CDIM + h * DHEAD + dg * 8) =
        o.v8;
  }
}

extern "C" void kernel_launch(void* const* d_in, const int* in_sizes, int n_in,
                              void* d_out, int out_size, void* d_ws,
                              size_t ws_size, hipStream_t stream) {
  const float* query = (const float*)d_in[0];
  const float* query_pos = (const float*)d_in[1];
  const float* W_val = (const float*)d_in[2];
  const float* b_val = (const float*)d_in[3];
  const float* W_off = (const float*)d_in[4];
  const float* b_off = (const float*)d_in[5];
  const float* W_attn = (const float*)d_in[6];
  const float* b_attn = (const float*)d_in[7];
  const float* W_out1 = (const float*)d_in[8];
  const float* b_out1 = (const float*)d_in[9];
  const float* W_out2 = (const float*)d_in[10];
  const float* b_out2 = (const float*)d_in[11];
  float* out = (float*)d_out;

  char* ws = (char*)d_ws;
  __hip_bfloat16* value = (__hip_bfloat16*)ws;  // (B*NH,N,32) bf16
  ws += (size_t)MROWS * CDIM * 2;
  __hip_bfloat16* offb = (__hip_bfloat16*)ws;   // (B*NH,N,40) bf16
  ws += (size_t)MROWS * 160 * 2;
  float* attnb = (float*)ws;                    // (B*NH,N,20) f32
  ws += (size_t)MROWS * 80 * 4;
  __hip_bfloat16* outat = (__hip_bfloat16*)ws;  // (B,N,C) bf16
  ws += (size_t)MROWS * CDIM * 2;
  float* bcat = (float*)ws; ws += OPAD * 4;
  float* bc = (float*)ws; ws += 128 * 4;
  __hip_bfloat16* Wcat = (__hip_bfloat16*)ws; ws += (size_t)OPAD * 128 * 2;
  __hip_bfloat16* Wc_bf = (__hip_bfloat16*)ws;

  prep_kernel<<<OPAD + 128, 128, 0, stream>>>(
      W_val, b_val, W_off, b_off, W_attn, b_attn, W_out1, b_out1, W_out2,
      b_out2, Wcat, bcat, Wc_bf, bc);

  proj1_kernel<<<dim3(313, 2), 256, 0, stream>>>(query, query_pos, Wcat, bcat,
                                                 value, offb, attnb);

  sample_kernel<<<8 * NPT * NPT, 256, 0, stream>>>(value, offb, attnb, outat);

  proj2_kernel<<<dim3(313, 2), 256, 0, stream>>>(outat, Wc_bf, bc, query, out);
}